// Round 7
// baseline (6442.764 us; speedup 1.0000x reference)
//
#include <hip/hip_runtime.h>

typedef _Float16 f16;
typedef f16   f16x8 __attribute__((ext_vector_type(8)));
typedef float f32x4 __attribute__((ext_vector_type(4)));
typedef unsigned long long u64;
typedef u64 u64x2 __attribute__((ext_vector_type(2)));

#define T_LEN 512
#define BATCH 64
#define HID   512

__device__ __forceinline__ float sigm(float x) { return 1.0f / (1.0f + __expf(-x)); }
__device__ __forceinline__ float tanh_f(float x) {
  x = fminf(fmaxf(x, -15.0f), 15.0f);
  float e = __expf(2.0f * x);
  return (e - 1.0f) / (e + 1.0f);
}

// write-through coherent 2B store: at the coherence point (L3) once vmcnt
// retires (proven R4-R6: passes with no buffer_wbl2 anywhere).
__device__ __forceinline__ void st_coh16(f16* p, f16 v) {
  unsigned int b = (unsigned int)__builtin_bit_cast(unsigned short, v);
  asm volatile("global_store_short %0, %1, off sc0 sc1" :: "v"(p), "v"(b) : "memory");
}

// agent-coherent 16B load (2x8B relaxed atomics; L2-bypassing, reads L3).
__device__ __forceinline__ f16x8 ld_coh(const f16* p) {
  u64x2 v;
  v.x = __hip_atomic_load((const u64*)p,     __ATOMIC_RELAXED, __HIP_MEMORY_SCOPE_AGENT);
  v.y = __hip_atomic_load((const u64*)p + 1, __ATOMIC_RELAXED, __HIP_MEMORY_SCOPE_AGENT);
  return __builtin_bit_cast(f16x8, v);
}

// ---- flag-array sync: NO atomic RMWs on the critical path ----------------
// Producer: drain data stores, then one posted relaxed flag STORE.
__device__ __forceinline__ void flag_set(unsigned* slot, unsigned val) {
  asm volatile("s_waitcnt vmcnt(0)" ::: "memory");   // my wave's stores at L3
  __syncthreads();                                   // => whole WG's stores at L3
  if (threadIdx.x == 0)
    __hip_atomic_store(slot, val, __ATOMIC_RELAXED, __HIP_MEMORY_SCOPE_AGENT);
}

// Waiter: wave 0 polls nf flags with ONE lane-parallel load per iteration;
// lanes < nlo require f[lane] >= tgt_lo, lanes nlo..nf-1 require >= tgt_hi.
__device__ __forceinline__ void flag_wait(const unsigned* f, int nf,
                                          unsigned tgt_lo, int nlo, unsigned tgt_hi) {
  if (threadIdx.x < 64) {
    const int lane = threadIdx.x;
    const int idx = (lane < nf) ? lane : 0;
    const unsigned tgt = (lane < nlo) ? tgt_lo : tgt_hi;
    for (;;) {
      unsigned v = __hip_atomic_load(f + idx, __ATOMIC_RELAXED,
                                     __HIP_MEMORY_SCOPE_AGENT);
      if (__all((lane >= nf) || (v >= tgt))) break;
      __builtin_amdgcn_s_sleep(1);
    }
  }
  __syncthreads();
}

// Fused recurrence, flag-array sync, 96 blocks (1 WG/CU, 128 KB dyn LDS):
//   blocks 0..31 : layer-1, 16 WGs/dir x 32 cols; waits only on own 16 flags
//                  (runs ahead of layer-2 freely; C1 is T-deep).
//   blocks 32..95: layer-2, 32 WGs/dir x 16 cols; one combined 48-lane poll:
//                  own 32 flags >= t (h2 dbuf safety) + l1's 16 >= t+1 (c1[t]).
__global__ __launch_bounds__(256) void lstm_fused(
    const float* __restrict__ w_ih1, const float* __restrict__ w_hh1,
    const float* __restrict__ b_ih1, const float* __restrict__ b_hh1,
    const float* __restrict__ w_ih2, const float* __restrict__ w_hh2,
    const float* __restrict__ b_ih2, const float* __restrict__ b_hh2,
    const float* __restrict__ w_ih3, const float* __restrict__ w_hh3,
    const float* __restrict__ b_ih3, const float* __restrict__ b_hh3,
    const float* __restrict__ w_ih4, const float* __restrict__ w_hh4,
    const float* __restrict__ b_ih4, const float* __restrict__ b_hh4,
    const float* __restrict__ x,
    f16* __restrict__ C1, f16* __restrict__ Y,
    f16* __restrict__ h1buf, f16* __restrict__ h2buf,
    unsigned* __restrict__ flags)
{
  extern __shared__ f16 wlds[];         // 128 KB dynamic
  const int tid = threadIdx.x;
  const int lane = tid & 63, wave = tid >> 6;
  const int col = lane & 15, quad = lane >> 4;
  const int m0 = wave * 16, b0 = m0 + quad * 4;

  if (blockIdx.x < 32) {
    // ---------------- layer-1 role: 32 cols, K=512, 8 N-tiles ----------------
    const int dir = blockIdx.x >> 4, wg = blockIdx.x & 15, j0 = wg * 32;
    const float* whh = dir ? w_hh3 : w_hh1;
    const float* wih = dir ? w_ih3 : w_ih1;
    const float* bi  = dir ? b_ih3 : b_ih1;
    const float* bh  = dir ? b_hh3 : b_hh1;
    // per-dir flag block: [0..31]=l2 flags, [32..47]=l1 flags
    unsigned* fdir = flags + dir * 64;
    unsigned* l1f  = fdir + 32;

    // stage weights into MFMA B-frag order; tile n: gate g=n&3, half=n>>2
    for (int idx = tid; idx < 8 * 16 * 64; idx += 256) {
      const int n = idx >> 10, kk = (idx >> 6) & 15, L = idx & 63;
      const int r = L & 15, q = L >> 4;
      const int g = n & 3, half = n >> 2;
      const float* src = whh + (size_t)(g * 512 + j0 + half * 16 + r) * HID
                             + kk * 32 + q * 8;
      f16* dst = wlds + idx * 8;
#pragma unroll
      for (int j = 0; j < 8; ++j) dst[j] = (f16)src[j];
    }

    float bias[2][4], wx[2][4];
#pragma unroll
    for (int half = 0; half < 2; ++half)
#pragma unroll
      for (int g = 0; g < 4; ++g) {
        const int row = g * 512 + j0 + half * 16 + col;
        bias[half][g] = bi[row] + bh[row];
        wx[half][g]   = wih[row];        // w_ih is [4H][1]
      }
    float cst[2][4] = {{0.f,0.f,0.f,0.f},{0.f,0.f,0.f,0.f}};

    f16* C1d = C1 + (size_t)dir * T_LEN * BATCH * HID;
    f16* hb  = h1buf + (size_t)dir * 2 * BATCH * HID;
    __syncthreads();

    for (int t = 0; t < T_LEN; ++t) {
      // wait: all l1 WGs of my dir finished step t-1 (h dbuf safe to read/write)
      flag_wait(l1f, 16, (unsigned)t, 16, (unsigned)t);

      const f16* hA = hb + (t & 1) * BATCH * HID;
      f16*       hN = hb + ((t + 1) & 1) * BATCH * HID;
      const f16* aptr = hA + (size_t)(m0 + col) * HID + quad * 8;
      f16x8 a[16];
#pragma unroll
      for (int kk = 0; kk < 16; ++kk) a[kk] = ld_coh(aptr + kk * 32);

      f32x4 acc[8];
#pragma unroll
      for (int n = 0; n < 8; ++n) acc[n] = (f32x4){0.f, 0.f, 0.f, 0.f};
#pragma unroll
      for (int kk = 0; kk < 16; ++kk) {
#pragma unroll
        for (int n = 0; n < 8; ++n) {
          f16x8 b = *(const f16x8*)(wlds + ((n * 16 + kk) * 64 + lane) * 8);
          acc[n] = __builtin_amdgcn_mfma_f32_16x16x32_f16(a[kk], b, acc[n], 0, 0, 0);
        }
      }

      const int teff = dir ? (T_LEN - 1 - t) : t;
      f16* c1row = C1d + (size_t)t * BATCH * HID;
#pragma unroll
      for (int half = 0; half < 2; ++half) {
        const int jg = j0 + half * 16 + col;
#pragma unroll
        for (int r = 0; r < 4; ++r) {
          const float xv = x[(size_t)(b0 + r) * T_LEN + teff];
          const float gi = sigm(acc[0 + half * 4][r] + wx[half][0] * xv + bias[half][0]);
          const float gf = sigm(acc[1 + half * 4][r] + wx[half][1] * xv + bias[half][1]);
          const float gg = tanh_f(acc[2 + half * 4][r] + wx[half][2] * xv + bias[half][2]);
          const float go = sigm(acc[3 + half * 4][r] + wx[half][3] * xv + bias[half][3]);
          const float c = gf * cst[half][r] + gi * gg;
          cst[half][r] = c;
          const float h = go * tanh_f(c);
          const int b = b0 + r;
          st_coh16(c1row + (size_t)b * HID + jg, (f16)c);
          st_coh16(hN + (size_t)b * HID + jg, (f16)h);
        }
      }
      // publish: c1[t] and h1[t] are at L3
      flag_set(&l1f[wg], (unsigned)(t + 1));
    }
  } else {
    // ---------------- layer-2 role: 16 cols, K=1024, 4 N-tiles (one/gate) ----
    const int bb = blockIdx.x - 32;
    const int dir = bb >> 5, wg = bb & 31, j0 = wg * 16;
    const float* wih = dir ? w_ih4 : w_ih2;
    const float* whh = dir ? w_hh4 : w_hh2;
    const float* bi  = dir ? b_ih4 : b_ih2;
    const float* bh  = dir ? b_hh4 : b_hh2;
    unsigned* fdir = flags + dir * 64;   // [0..31]=l2, [32..47]=l1

    // tile n = gate; K = [c1 (kk 0..15) | h2 (kk 16..31)]
    for (int idx = tid; idx < 4 * 32 * 64; idx += 256) {
      const int n = idx >> 11, kk = (idx >> 6) & 31, L = idx & 63;
      const int r = L & 15, q = L >> 4;
      const int grow = n * 512 + j0 + r;
      const int k = kk * 32 + q * 8;
      const float* src = (k < 512) ? (wih + (size_t)grow * HID + k)
                                   : (whh + (size_t)grow * HID + (k - 512));
      f16* dst = wlds + idx * 8;
#pragma unroll
      for (int j = 0; j < 8; ++j) dst[j] = (f16)src[j];
    }

    const int jg = j0 + col;
    float bias[4];
#pragma unroll
    for (int g = 0; g < 4; ++g) bias[g] = bi[g * 512 + jg] + bh[g * 512 + jg];
    float cst[4] = {0.f, 0.f, 0.f, 0.f};

    const f16* C1d = C1 + (size_t)dir * T_LEN * BATCH * HID;
    f16* Yd = Y + (size_t)dir * T_LEN * BATCH * HID;
    f16* hb = h2buf + (size_t)dir * 2 * BATCH * HID;
    __syncthreads();

    for (int t = 0; t < T_LEN; ++t) {
      // combined wait: own l2 flags >= t  AND  l1 flags >= t+1 (c1[t] ready)
      flag_wait(fdir, 48, (unsigned)t, 32, (unsigned)(t + 1));

      const f16* c1t = C1d + (size_t)t * BATCH * HID;
      const f16* hA = hb + (t & 1) * BATCH * HID;
      f16*       hN = hb + ((t + 1) & 1) * BATCH * HID;
      const f16* aptrC = c1t + (size_t)(m0 + col) * HID + quad * 8;
      const f16* aptrH = hA  + (size_t)(m0 + col) * HID + quad * 8;

      f16x8 a[32];
#pragma unroll
      for (int kk = 0; kk < 16; ++kk) a[kk]      = ld_coh(aptrC + kk * 32);
#pragma unroll
      for (int kk = 0; kk < 16; ++kk) a[16 + kk] = ld_coh(aptrH + kk * 32);

      f32x4 acc[4];
#pragma unroll
      for (int n = 0; n < 4; ++n) acc[n] = (f32x4){0.f, 0.f, 0.f, 0.f};
#pragma unroll
      for (int kk = 0; kk < 32; ++kk) {
#pragma unroll
        for (int n = 0; n < 4; ++n) {
          f16x8 b = *(const f16x8*)(wlds + ((n * 32 + kk) * 64 + lane) * 8);
          acc[n] = __builtin_amdgcn_mfma_f32_16x16x32_f16(a[kk], b, acc[n], 0, 0, 0);
        }
      }

      f16* yrow = Yd + (size_t)t * BATCH * HID;
#pragma unroll
      for (int r = 0; r < 4; ++r) {
        const float gi = sigm(acc[0][r] + bias[0]);
        const float gf = sigm(acc[1][r] + bias[1]);
        const float gg = tanh_f(acc[2][r] + bias[2]);
        const float go = sigm(acc[3][r] + bias[3]);
        const float c = gf * cst[r] + gi * gg;
        cst[r] = c;
        const float h = go * tanh_f(c);
        const int b = b0 + r;
        yrow[(size_t)b * HID + jg] = (f16)c;   // plain: consumed after kernel end
        st_coh16(hN + (size_t)b * HID + jg, (f16)h);
      }
      flag_set(&fdir[wg], (unsigned)(t + 1));
    }
  }
}

// ---------- output FC, both directions ----------
__global__ __launch_bounds__(256) void fc_out(
    const f16* __restrict__ Y,
    const float* __restrict__ fw, const float* __restrict__ fb,
    const float* __restrict__ bw, const float* __restrict__ bb,
    float* __restrict__ out)
{
  const int dir = blockIdx.x >> 9;
  const int t = blockIdx.x & 511;
  const int tid = threadIdx.x;
  const int b = tid & 63;
  const int c0 = (tid >> 6) * 16;
  const float* W  = dir ? bw : fw;
  const float* Bv = dir ? bb : fb;
  const f16* yrow = Y + ((size_t)(dir * T_LEN + t) * BATCH + b) * HID;

  float acc[16];
#pragma unroll
  for (int c = 0; c < 16; ++c) acc[c] = 0.f;

  for (int k = 0; k < HID; k += 8) {
    f16x8 yv = *(const f16x8*)(yrow + k);
    float yf[8];
#pragma unroll
    for (int j = 0; j < 8; ++j) yf[j] = (float)yv[j];
#pragma unroll
    for (int c = 0; c < 16; ++c) {
      const float* wr = W + (size_t)(c0 + c) * HID + k;
      const float4 w0 = *(const float4*)wr;
      const float4 w1 = *(const float4*)(wr + 4);
      acc[c] += yf[0] * w0.x + yf[1] * w0.y + yf[2] * w0.z + yf[3] * w0.w
              + yf[4] * w1.x + yf[5] * w1.y + yf[6] * w1.z + yf[7] * w1.w;
    }
  }
  float* orow = out + (size_t)dir * (BATCH * T_LEN * 64)
                    + ((size_t)b * T_LEN + t) * 64 + c0;
#pragma unroll
  for (int c = 0; c < 16; ++c) orow[c] = acc[c] + Bv[c0 + c];
}

// ---------- launch ----------
extern "C" void kernel_launch(void* const* d_in, const int* in_sizes, int n_in,
                              void* d_out, int out_size, void* d_ws, size_t ws_size,
                              hipStream_t stream) {
  const float* x     = (const float*)d_in[0];
  const float* w_ih1 = (const float*)d_in[1];
  const float* w_hh1 = (const float*)d_in[2];
  const float* b_ih1 = (const float*)d_in[3];
  const float* b_hh1 = (const float*)d_in[4];
  const float* w_ih2 = (const float*)d_in[5];
  const float* w_hh2 = (const float*)d_in[6];
  const float* b_ih2 = (const float*)d_in[7];
  const float* b_hh2 = (const float*)d_in[8];
  const float* w_ih3 = (const float*)d_in[9];
  const float* w_hh3 = (const float*)d_in[10];
  const float* b_ih3 = (const float*)d_in[11];
  const float* b_hh3 = (const float*)d_in[12];
  const float* w_ih4 = (const float*)d_in[13];
  const float* w_hh4 = (const float*)d_in[14];
  const float* b_ih4 = (const float*)d_in[15];
  const float* b_hh4 = (const float*)d_in[16];
  const float* fc_w  = (const float*)d_in[17];
  const float* fc_b  = (const float*)d_in[18];
  const float* bfc_w = (const float*)d_in[19];
  const float* bfc_b = (const float*)d_in[20];

  // ws layout (bytes):
  //   [h1 256KB][h2 256KB][flags 512B][pad][C1 64MB][Y 64MB]
  char* ws = (char*)d_ws;
  f16* h1b = (f16*)(ws);
  f16* h2b = (f16*)(ws + 262144);
  unsigned* flags = (unsigned*)(ws + 524288);   // [2 dirs][64] (0..31 l2, 32..47 l1)
  const size_t SEQ_BYTES = (size_t)2 * T_LEN * BATCH * HID * sizeof(f16); // 64 MB
  f16* C1 = (f16*)(ws + 532480);
  f16* Yb = (f16*)(ws + 532480 + SEQ_BYTES);

  // zero h-state buffers + flags (ws is poisoned 0xAA each launch)
  hipMemsetAsync(ws, 0, 526848, stream);

  // raise dynamic-LDS cap to 128 KB (host-side config call, capture-safe)
  static bool lds_set = false;
  if (!lds_set) {
    hipFuncSetAttribute((const void*)lstm_fused,
                        hipFuncAttributeMaxDynamicSharedMemorySize, 131072);
    lds_set = true;
  }

  lstm_fused<<<96, 256, 131072, stream>>>(
      w_ih1, w_hh1, b_ih1, b_hh1, w_ih2, w_hh2, b_ih2, b_hh2,
      w_ih3, w_hh3, b_ih3, b_hh3, w_ih4, w_hh4, b_ih4, b_hh4,
      x, C1, Yb, h1b, h2b, flags);
  fc_out<<<1024, 256, 0, stream>>>(Yb, fc_w, fc_b, bfc_w, bfc_b, (float*)d_out);
}

// Round 8
// 5889.086 us; speedup vs baseline: 1.0940x; 1.0940x over previous
//
#include <hip/hip_runtime.h>

typedef _Float16 f16;
typedef f16   f16x8 __attribute__((ext_vector_type(8)));
typedef float f32x4 __attribute__((ext_vector_type(4)));

#define T_LEN 512
#define BATCH 64
#define HID   512

__device__ __forceinline__ float sigm(float x) { return 1.0f / (1.0f + __expf(-x)); }
__device__ __forceinline__ float tanh_f(float x) {
  x = fminf(fmaxf(x, -15.0f), 15.0f);
  float e = __expf(2.0f * x);
  return (e - 1.0f) / (e + 1.0f);
}

// write-through coherent 2B store: at the coherence point (L3) once vmcnt
// retires (proven R4-R7: passes with no buffer_wbl2 anywhere).
__device__ __forceinline__ void st_coh16(f16* p, f16 v) {
  unsigned int b = (unsigned int)__builtin_bit_cast(unsigned short, v);
  asm volatile("global_store_short %0, %1, off sc0 sc1" :: "v"(p), "v"(b) : "memory");
}

// Joint per-dir sync over nf WGs — R4 semantics, flag-array mechanism:
//   release: write-through data stores + vmcnt(0) drain in all waves,
//            then ONE posted relaxed flag store (no RMW).
//   wait:    wave 0 polls all nf flags with one lane-parallel load/iter.
//   acquire: agent fence (inv) so next step's PLAIN cached loads refetch.
__device__ __forceinline__ void joint_sync(unsigned* f, int nf, int myflag,
                                           unsigned tgt) {
  asm volatile("s_waitcnt vmcnt(0)" ::: "memory");   // my wave's stores at L3
  __syncthreads();                                   // whole WG's stores at L3
  if (threadIdx.x == 0)
    __hip_atomic_store(f + myflag, tgt, __ATOMIC_RELAXED, __HIP_MEMORY_SCOPE_AGENT);
  if (threadIdx.x < 64) {
    const int lane = threadIdx.x;
    const int idx = (lane < nf) ? lane : 0;
    for (;;) {
      unsigned v = __hip_atomic_load(f + idx, __ATOMIC_RELAXED,
                                     __HIP_MEMORY_SCOPE_AGENT);
      if (__all(v >= tgt)) break;
      __builtin_amdgcn_s_sleep(1);
    }
    __builtin_amdgcn_fence(__ATOMIC_ACQUIRE, "agent");  // inv before plain re-reads
  }
  __syncthreads();
}

// Fused skewed recurrence (R4 structure), 96 blocks (1 WG/CU, 128 KB dyn LDS):
//   blocks 0..31 : layer-1, 16 WGs/dir x 32 cols, t = s
//   blocks 32..95: layer-2, 32 WGs/dir x 16 cols, t = s-1
// Per direction 48 WGs share ONE joint flag-sync per step; 513 skewed steps.
__global__ __launch_bounds__(256) void lstm_fused(
    const float* __restrict__ w_ih1, const float* __restrict__ w_hh1,
    const float* __restrict__ b_ih1, const float* __restrict__ b_hh1,
    const float* __restrict__ w_ih2, const float* __restrict__ w_hh2,
    const float* __restrict__ b_ih2, const float* __restrict__ b_hh2,
    const float* __restrict__ w_ih3, const float* __restrict__ w_hh3,
    const float* __restrict__ b_ih3, const float* __restrict__ b_hh3,
    const float* __restrict__ w_ih4, const float* __restrict__ w_hh4,
    const float* __restrict__ b_ih4, const float* __restrict__ b_hh4,
    const float* __restrict__ x,
    f16* __restrict__ C1, f16* __restrict__ Y,
    f16* __restrict__ h1buf, f16* __restrict__ h2buf,
    unsigned* __restrict__ flags)
{
  extern __shared__ f16 wlds[];         // 128 KB dynamic
  const int tid = threadIdx.x;
  const int lane = tid & 63, wave = tid >> 6;
  const int col = lane & 15, quad = lane >> 4;
  const int m0 = wave * 16, b0 = m0 + quad * 4;

  if (blockIdx.x < 32) {
    // ---------------- layer-1 role: 32 cols, K=512, 8 N-tiles ----------------
    const int dir = blockIdx.x >> 4, wg = blockIdx.x & 15, j0 = wg * 32;
    const float* whh = dir ? w_hh3 : w_hh1;
    const float* wih = dir ? w_ih3 : w_ih1;
    const float* bi  = dir ? b_ih3 : b_ih1;
    const float* bh  = dir ? b_hh3 : b_hh1;
    unsigned* fdir = flags + dir * 64;   // [0..15]=l1 WGs, [16..47]=l2 WGs

    // stage weights into MFMA B-frag order; tile n: gate g=n&3, half=n>>2
    for (int idx = tid; idx < 8 * 16 * 64; idx += 256) {
      const int n = idx >> 10, kk = (idx >> 6) & 15, L = idx & 63;
      const int r = L & 15, q = L >> 4;
      const int g = n & 3, half = n >> 2;
      const float* src = whh + (size_t)(g * 512 + j0 + half * 16 + r) * HID
                             + kk * 32 + q * 8;
      f16* dst = wlds + idx * 8;
#pragma unroll
      for (int j = 0; j < 8; ++j) dst[j] = (f16)src[j];
    }

    float bias[2][4], wx[2][4];
#pragma unroll
    for (int half = 0; half < 2; ++half)
#pragma unroll
      for (int g = 0; g < 4; ++g) {
        const int row = g * 512 + j0 + half * 16 + col;
        bias[half][g] = bi[row] + bh[row];
        wx[half][g]   = wih[row];        // w_ih is [4H][1]
      }
    float cst[2][4] = {{0.f,0.f,0.f,0.f},{0.f,0.f,0.f,0.f}};

    f16* C1d = C1 + (size_t)dir * T_LEN * BATCH * HID;
    f16* hb  = h1buf + (size_t)dir * 2 * BATCH * HID;
    __syncthreads();

    for (int t = 0; t < T_LEN; ++t) {
      const f16* hA = hb + (t & 1) * BATCH * HID;
      f16*       hN = hb + ((t + 1) & 1) * BATCH * HID;
      const f16* aptr = hA + (size_t)(m0 + col) * HID + quad * 8;
      f16x8 a[16];
#pragma unroll
      for (int kk = 0; kk < 16; ++kk) a[kk] = *(const f16x8*)(aptr + kk * 32);

      f32x4 acc[8];
#pragma unroll
      for (int n = 0; n < 8; ++n) acc[n] = (f32x4){0.f, 0.f, 0.f, 0.f};
#pragma unroll
      for (int kk = 0; kk < 16; ++kk) {
#pragma unroll
        for (int n = 0; n < 8; ++n) {
          f16x8 b = *(const f16x8*)(wlds + ((n * 16 + kk) * 64 + lane) * 8);
          acc[n] = __builtin_amdgcn_mfma_f32_16x16x32_f16(a[kk], b, acc[n], 0, 0, 0);
        }
      }

      const int teff = dir ? (T_LEN - 1 - t) : t;
      f16* c1row = C1d + (size_t)t * BATCH * HID;
#pragma unroll
      for (int half = 0; half < 2; ++half) {
        const int jg = j0 + half * 16 + col;
#pragma unroll
        for (int r = 0; r < 4; ++r) {
          const float xv = x[(size_t)(b0 + r) * T_LEN + teff];
          const float gi = sigm(acc[0 + half * 4][r] + wx[half][0] * xv + bias[half][0]);
          const float gf = sigm(acc[1 + half * 4][r] + wx[half][1] * xv + bias[half][1]);
          const float gg = tanh_f(acc[2 + half * 4][r] + wx[half][2] * xv + bias[half][2]);
          const float go = sigm(acc[3 + half * 4][r] + wx[half][3] * xv + bias[half][3]);
          const float c = gf * cst[half][r] + gi * gg;
          cst[half][r] = c;
          const float h = go * tanh_f(c);
          const int b = b0 + r;
          st_coh16(c1row + (size_t)b * HID + jg, (f16)c);
          st_coh16(hN + (size_t)b * HID + jg, (f16)h);
        }
      }
      joint_sync(fdir, 48, wg, (unsigned)(t + 1));
    }
  } else {
    // ---------------- layer-2 role: 16 cols, K=1024, 4 N-tiles (one/gate) ----
    const int bb = blockIdx.x - 32;
    const int dir = bb >> 5, wg = bb & 31, j0 = wg * 16;
    const float* wih = dir ? w_ih4 : w_ih2;
    const float* whh = dir ? w_hh4 : w_hh2;
    const float* bi  = dir ? b_ih4 : b_ih2;
    const float* bh  = dir ? b_hh4 : b_hh2;
    unsigned* fdir = flags + dir * 64;   // [0..15]=l1, [16..47]=l2

    // tile n = gate; K = [c1 (kk 0..15) | h2 (kk 16..31)]
    for (int idx = tid; idx < 4 * 32 * 64; idx += 256) {
      const int n = idx >> 11, kk = (idx >> 6) & 31, L = idx & 63;
      const int r = L & 15, q = L >> 4;
      const int grow = n * 512 + j0 + r;
      const int k = kk * 32 + q * 8;
      const float* src = (k < 512) ? (wih + (size_t)grow * HID + k)
                                   : (whh + (size_t)grow * HID + (k - 512));
      f16* dst = wlds + idx * 8;
#pragma unroll
      for (int j = 0; j < 8; ++j) dst[j] = (f16)src[j];
    }

    const int jg = j0 + col;
    float bias[4];
#pragma unroll
    for (int g = 0; g < 4; ++g) bias[g] = bi[g * 512 + jg] + bh[g * 512 + jg];
    float cst[4] = {0.f, 0.f, 0.f, 0.f};

    const f16* C1d = C1 + (size_t)dir * T_LEN * BATCH * HID;
    f16* Yd = Y + (size_t)dir * T_LEN * BATCH * HID;
    f16* hb = h2buf + (size_t)dir * 2 * BATCH * HID;
    __syncthreads();

    for (int s = 0; s < 513; ++s) {
      if (s >= 1) {
        const int t = s - 1;
        const f16* c1t = C1d + (size_t)t * BATCH * HID;
        const f16* hA = hb + (t & 1) * BATCH * HID;
        f16*       hN = hb + ((t + 1) & 1) * BATCH * HID;
        const f16* aptrC = c1t + (size_t)(m0 + col) * HID + quad * 8;
        const f16* aptrH = hA  + (size_t)(m0 + col) * HID + quad * 8;
        f16x8 a[32];
#pragma unroll
        for (int kk = 0; kk < 16; ++kk) a[kk]      = *(const f16x8*)(aptrC + kk * 32);
#pragma unroll
        for (int kk = 0; kk < 16; ++kk) a[16 + kk] = *(const f16x8*)(aptrH + kk * 32);

        f32x4 acc[4];
#pragma unroll
        for (int n = 0; n < 4; ++n) acc[n] = (f32x4){0.f, 0.f, 0.f, 0.f};
#pragma unroll
        for (int kk = 0; kk < 32; ++kk) {
#pragma unroll
          for (int n = 0; n < 4; ++n) {
            f16x8 b = *(const f16x8*)(wlds + ((n * 32 + kk) * 64 + lane) * 8);
            acc[n] = __builtin_amdgcn_mfma_f32_16x16x32_f16(a[kk], b, acc[n], 0, 0, 0);
          }
        }
        f16* yrow = Yd + (size_t)t * BATCH * HID;
#pragma unroll
        for (int r = 0; r < 4; ++r) {
          const float gi = sigm(acc[0][r] + bias[0]);
          const float gf = sigm(acc[1][r] + bias[1]);
          const float gg = tanh_f(acc[2][r] + bias[2]);
          const float go = sigm(acc[3][r] + bias[3]);
          const float c = gf * cst[r] + gi * gg;
          cst[r] = c;
          const float h = go * tanh_f(c);
          const int b = b0 + r;
          yrow[(size_t)b * HID + jg] = (f16)c;   // plain: consumed after kernel end
          st_coh16(hN + (size_t)b * HID + jg, (f16)h);
        }
      }
      if (s < 512) joint_sync(fdir, 48, 16 + wg, (unsigned)(s + 1));
    }
  }
}

// ---------- output FC, both directions ----------
__global__ __launch_bounds__(256) void fc_out(
    const f16* __restrict__ Y,
    const float* __restrict__ fw, const float* __restrict__ fb,
    const float* __restrict__ bw, const float* __restrict__ bb,
    float* __restrict__ out)
{
  const int dir = blockIdx.x >> 9;
  const int t = blockIdx.x & 511;
  const int tid = threadIdx.x;
  const int b = tid & 63;
  const int c0 = (tid >> 6) * 16;
  const float* W  = dir ? bw : fw;
  const float* Bv = dir ? bb : fb;
  const f16* yrow = Y + ((size_t)(dir * T_LEN + t) * BATCH + b) * HID;

  float acc[16];
#pragma unroll
  for (int c = 0; c < 16; ++c) acc[c] = 0.f;

  for (int k = 0; k < HID; k += 8) {
    f16x8 yv = *(const f16x8*)(yrow + k);
    float yf[8];
#pragma unroll
    for (int j = 0; j < 8; ++j) yf[j] = (float)yv[j];
#pragma unroll
    for (int c = 0; c < 16; ++c) {
      const float* wr = W + (size_t)(c0 + c) * HID + k;
      const float4 w0 = *(const float4*)wr;
      const float4 w1 = *(const float4*)(wr + 4);
      acc[c] += yf[0] * w0.x + yf[1] * w0.y + yf[2] * w0.z + yf[3] * w0.w
              + yf[4] * w1.x + yf[5] * w1.y + yf[6] * w1.z + yf[7] * w1.w;
    }
  }
  float* orow = out + (size_t)dir * (BATCH * T_LEN * 64)
                    + ((size_t)b * T_LEN + t) * 64 + c0;
#pragma unroll
  for (int c = 0; c < 16; ++c) orow[c] = acc[c] + Bv[c0 + c];
}

// ---------- launch ----------
extern "C" void kernel_launch(void* const* d_in, const int* in_sizes, int n_in,
                              void* d_out, int out_size, void* d_ws, size_t ws_size,
                              hipStream_t stream) {
  const float* x     = (const float*)d_in[0];
  const float* w_ih1 = (const float*)d_in[1];
  const float* w_hh1 = (const float*)d_in[2];
  const float* b_ih1 = (const float*)d_in[3];
  const float* b_hh1 = (const float*)d_in[4];
  const float* w_ih2 = (const float*)d_in[5];
  const float* w_hh2 = (const float*)d_in[6];
  const float* b_ih2 = (const float*)d_in[7];
  const float* b_hh2 = (const float*)d_in[8];
  const float* w_ih3 = (const float*)d_in[9];
  const float* w_hh3 = (const float*)d_in[10];
  const float* b_ih3 = (const float*)d_in[11];
  const float* b_hh3 = (const float*)d_in[12];
  const float* w_ih4 = (const float*)d_in[13];
  const float* w_hh4 = (const float*)d_in[14];
  const float* b_ih4 = (const float*)d_in[15];
  const float* b_hh4 = (const float*)d_in[16];
  const float* fc_w  = (const float*)d_in[17];
  const float* fc_b  = (const float*)d_in[18];
  const float* bfc_w = (const float*)d_in[19];
  const float* bfc_b = (const float*)d_in[20];

  // ws layout (bytes):
  //   [h1 256KB][h2 256KB][flags 512B][pad][C1 64MB][Y 64MB]
  char* ws = (char*)d_ws;
  f16* h1b = (f16*)(ws);
  f16* h2b = (f16*)(ws + 262144);
  unsigned* flags = (unsigned*)(ws + 524288);   // [2 dirs][64] (0..15 l1, 16..47 l2)
  const size_t SEQ_BYTES = (size_t)2 * T_LEN * BATCH * HID * sizeof(f16); // 64 MB
  f16* C1 = (f16*)(ws + 532480);
  f16* Yb = (f16*)(ws + 532480 + SEQ_BYTES);

  // zero h-state buffers + flags (ws is poisoned 0xAA each launch)
  hipMemsetAsync(ws, 0, 526848, stream);

  // raise dynamic-LDS cap to 128 KB (host-side config call, capture-safe)
  static bool lds_set = false;
  if (!lds_set) {
    hipFuncSetAttribute((const void*)lstm_fused,
                        hipFuncAttributeMaxDynamicSharedMemorySize, 131072);
    lds_set = true;
  }

  lstm_fused<<<96, 256, 131072, stream>>>(
      w_ih1, w_hh1, b_ih1, b_hh1, w_ih2, w_hh2, b_ih2, b_hh2,
      w_ih3, w_hh3, b_ih3, b_hh3, w_ih4, w_hh4, b_ih4, b_hh4,
      x, C1, Yb, h1b, h2b, flags);
  fc_out<<<1024, 256, 0, stream>>>(Yb, fc_w, fc_b, bfc_w, bfc_b, (float*)d_out);
}